// Round 12
// baseline (132.308 us; speedup 1.0000x reference)
//
#include <hip/hip_runtime.h>

#define BATCH   32768
#define SD      256
#define LD      64
#define HDIM    64
#define NEMB    2048
#define REFINE_THR_Q 5e-4f   // gap in q-units; s-gap = 2*q-gap -> 1e-3 effective

typedef short  short8 __attribute__((ext_vector_type(8)));
typedef float  f32x4  __attribute__((ext_vector_type(4)));

__device__ __forceinline__ unsigned short f2bf(float f) {
    unsigned int u = __float_as_uint(f);
    u = (u + 0x7FFFu + ((u >> 16) & 1u)) >> 16;
    return (unsigned short)u;
}
__device__ __forceinline__ float bf2f(unsigned short h) {
    return __uint_as_float(((unsigned int)h) << 16);
}

// ---------------------------------------------------------------------------
// K0: e2q[k] = -0.5*||emb[k]||^2, bf16 split eh/el, zero refine counter.
// ---------------------------------------------------------------------------
__global__ __launch_bounds__(256) void k0_prep(const float* __restrict__ emb,
                                               float* __restrict__ e2q,
                                               unsigned short* __restrict__ eh,
                                               unsigned short* __restrict__ el,
                                               int* __restrict__ count) {
    int k = blockIdx.x * 256 + threadIdx.x;
    if (k == 0) *count = 0;
    const float* er = emb + (size_t)k * LD;
    unsigned short hrow[LD], lrow[LD];
    float s = 0.f;
#pragma unroll
    for (int q = 0; q < LD; ++q) {
        float v = er[q];
        s += v * v;
        unsigned short h = f2bf(v);
        hrow[q] = h;
        lrow[q] = f2bf(v - bf2f(h));
    }
    e2q[k] = -0.5f * s;
    short8* dh = (short8*)(eh + (size_t)k * LD);
    short8* dl = (short8*)(el + (size_t)k * LD);
#pragma unroll
    for (int q = 0; q < 8; ++q) {
        dh[q] = *(short8*)&hrow[q * 8];
        dl[q] = *(short8*)&lrow[q * 8];
    }
}

// ---------------------------------------------------------------------------
// K0b: split decoder weights to bf16 h/l, TRANSPOSED to [j][k] for B-frags.
// ---------------------------------------------------------------------------
__global__ __launch_bounds__(256) void k0b_wsplit(const float* __restrict__ w1,
                                                  const float* __restrict__ w2,
                                                  unsigned short* __restrict__ w1h,
                                                  unsigned short* __restrict__ w1l,
                                                  unsigned short* __restrict__ w2h,
                                                  unsigned short* __restrict__ w2l) {
    int b = blockIdx.x;
    int t = threadIdx.x;
    if (b < 16) {
        int e = b * 256 + t;
        int j = e >> 6, k = e & 63;
        float v = w1[k * HDIM + j];
        unsigned short h = f2bf(v);
        w1h[e] = h; w1l[e] = f2bf(v - bf2f(h));
    } else {
        int e = (b - 16) * 256 + t;
        int j = e >> 6, k = e & 63;
        float v = w2[k * SD + j];
        unsigned short h = f2bf(v);
        w2h[e] = h; w2l[e] = f2bf(v - bf2f(h));
    }
}

// ---------------------------------------------------------------------------
// ENC v3: 8x8 outer-product register tiling, f32 exact.
// 512 blocks x 512 thr (8 waves), 64 rows/block, lane=(rg,cg) 8x8 grid,
// each lane acc[8r][8c]. L1: K=256 split 8 waves x 32k; per k: 2 b128 xT +
// 2 b128 w1 feed 64 FMA. Pairwise LDS tree-merge (red aliases dead xT).
// h stored transposed hs[j][i] (pad 66) -> L2 identical pattern (K=64, 8x8k).
// LDS exactly 128KB -> 1 block/CU, 2 grid rounds.
// ---------------------------------------------------------------------------
__device__ __forceinline__ void wr_slice(float* red, int s, float (&a)[8][8],
                                         int rg, int cg) {
#pragma unroll
    for (int cc = 0; cc < 8; ++cc) {
        float4 v0 = {a[0][cc], a[1][cc], a[2][cc], a[3][cc]};
        float4 v1 = {a[4][cc], a[5][cc], a[6][cc], a[7][cc]};
        float* p = red + s * 4096 + (cg * 8 + cc) * 64 + rg * 8;
        *(float4*)p = v0;
        *(float4*)(p + 4) = v1;
    }
}
__device__ __forceinline__ void add_slice(float* red, int s, float (&a)[8][8],
                                          int rg, int cg) {
#pragma unroll
    for (int cc = 0; cc < 8; ++cc) {
        const float* p = red + s * 4096 + (cg * 8 + cc) * 64 + rg * 8;
        float4 v0 = *(const float4*)p;
        float4 v1 = *(const float4*)(p + 4);
        a[0][cc] += v0.x; a[1][cc] += v0.y; a[2][cc] += v0.z; a[3][cc] += v0.w;
        a[4][cc] += v1.x; a[5][cc] += v1.y; a[6][cc] += v1.z; a[7][cc] += v1.w;
    }
}
__device__ __forceinline__ void enc_merge(float* red, float (&a)[8][8],
                                          int w, int rg, int cg) {
    if (w & 1) wr_slice(red, w >> 1, a, rg, cg);
    __syncthreads();
    if (!(w & 1)) add_slice(red, w >> 1, a, rg, cg);
    __syncthreads();
    if (w == 2) wr_slice(red, 0, a, rg, cg);
    if (w == 6) wr_slice(red, 1, a, rg, cg);
    __syncthreads();
    if (w == 0) add_slice(red, 0, a, rg, cg);
    if (w == 4) add_slice(red, 1, a, rg, cg);
    __syncthreads();
    if (w == 4) wr_slice(red, 0, a, rg, cg);
    __syncthreads();
    if (w == 0) add_slice(red, 0, a, rg, cg);
}

__global__ __launch_bounds__(512, 2) void k_enc(const float* __restrict__ x,
                                                const float* __restrict__ w1,
                                                const float* __restrict__ b1,
                                                const float* __restrict__ w2,
                                                const float* __restrict__ b2,
                                                float* __restrict__ zOut,
                                                unsigned short* __restrict__ zh,
                                                unsigned short* __restrict__ zl) {
    __shared__ float smem[32768];      // 128 KB
    float* xT  = smem;                 // [256][64]  (L1)
    float* w1s = smem + 16384;         // [256][64]  (L1)
    float* red = smem;                 // merge slices [4][64][64]
    float* w2s = smem + 16384;         // [64][64]   (L2)
    float* hs  = smem + 20480;         // [64][66]   (L2, padded)

    int tid  = threadIdx.x;
    int lane = tid & 63;
    int w    = tid >> 6;
    int rg   = lane & 7;
    int cg   = lane >> 3;
    int r0   = blockIdx.x * 64;

    // stage xT (transpose) + w1
    {
        int r = tid >> 3, kq = tid & 7;
        const float* xr = x + (size_t)(r0 + r) * SD;
#pragma unroll
        for (int p = 0; p < 8; ++p) {
            int k = p * 32 + kq * 4;
            float4 v = *(const float4*)(xr + k);
            xT[(k + 0) * 64 + r] = v.x;
            xT[(k + 1) * 64 + r] = v.y;
            xT[(k + 2) * 64 + r] = v.z;
            xT[(k + 3) * 64 + r] = v.w;
        }
        const float4* src = (const float4*)w1;
        float4* dst = (float4*)w1s;
#pragma unroll
        for (int t = 0; t < 8; ++t) dst[tid + 512 * t] = src[tid + 512 * t];
    }
    __syncthreads();

    // ---- L1 k-loop: wave w covers k = w*32 .. w*32+31
    float acc[8][8];
#pragma unroll
    for (int i = 0; i < 8; ++i)
#pragma unroll
        for (int j = 0; j < 8; ++j) acc[i][j] = 0.f;
    {
        int k0 = w * 32;
#pragma unroll 4
        for (int k = k0; k < k0 + 32; ++k) {
            float4 xa = *(const float4*)&xT[k * 64 + rg * 8];
            float4 xb = *(const float4*)&xT[k * 64 + rg * 8 + 4];
            float4 wa = *(const float4*)&w1s[k * 64 + cg * 8];
            float4 wb = *(const float4*)&w1s[k * 64 + cg * 8 + 4];
            float xf[8] = {xa.x, xa.y, xa.z, xa.w, xb.x, xb.y, xb.z, xb.w};
            float wf[8] = {wa.x, wa.y, wa.z, wa.w, wb.x, wb.y, wb.z, wb.w};
#pragma unroll
            for (int rr = 0; rr < 8; ++rr)
#pragma unroll
                for (int cc = 0; cc < 8; ++cc)
                    acc[rr][cc] = fmaf(xf[rr], wf[cc], acc[rr][cc]);
        }
    }
    __syncthreads();                    // xT/w1s dead; red/w2s/hs live next

    // stage w2 (into dead w1s region) while merge starts
    {
        const float4* src = (const float4*)w2;
        float4* dst = (float4*)w2s;
        dst[tid] = src[tid];
        dst[tid + 512] = src[tid + 512];
    }
    enc_merge(red, acc, w, rg, cg);

    // wave 0 finalizes h = relu(acc + b1), stores TRANSPOSED hs[j][i]
    if (w == 0) {
        float b1v[8];
        *(float4*)&b1v[0] = *(const float4*)(b1 + cg * 8);
        *(float4*)&b1v[4] = *(const float4*)(b1 + cg * 8 + 4);
#pragma unroll
        for (int cc = 0; cc < 8; ++cc) {
            int j = cg * 8 + cc;
            float4 h0 = {fmaxf(acc[0][cc] + b1v[cc], 0.f),
                         fmaxf(acc[1][cc] + b1v[cc], 0.f),
                         fmaxf(acc[2][cc] + b1v[cc], 0.f),
                         fmaxf(acc[3][cc] + b1v[cc], 0.f)};
            float4 h1 = {fmaxf(acc[4][cc] + b1v[cc], 0.f),
                         fmaxf(acc[5][cc] + b1v[cc], 0.f),
                         fmaxf(acc[6][cc] + b1v[cc], 0.f),
                         fmaxf(acc[7][cc] + b1v[cc], 0.f)};
            *(float4*)&hs[j * 66 + rg * 8] = h0;
            *(float4*)&hs[j * 66 + rg * 8 + 4] = h1;
        }
    }
    __syncthreads();

    // ---- L2 k-loop: wave w covers k2 = w*8 .. w*8+7
    float ac2[8][8];
#pragma unroll
    for (int i = 0; i < 8; ++i)
#pragma unroll
        for (int j = 0; j < 8; ++j) ac2[i][j] = 0.f;
    {
        int q0 = w * 8;
#pragma unroll
        for (int k2 = q0; k2 < q0 + 8; ++k2) {
            float4 xa = *(const float4*)&hs[k2 * 66 + rg * 8];
            float4 xb = *(const float4*)&hs[k2 * 66 + rg * 8 + 4];
            float4 wa = *(const float4*)&w2s[k2 * 64 + cg * 8];
            float4 wb = *(const float4*)&w2s[k2 * 64 + cg * 8 + 4];
            float xf[8] = {xa.x, xa.y, xa.z, xa.w, xb.x, xb.y, xb.z, xb.w};
            float wf[8] = {wa.x, wa.y, wa.z, wa.w, wb.x, wb.y, wb.z, wb.w};
#pragma unroll
            for (int rr = 0; rr < 8; ++rr)
#pragma unroll
                for (int cc = 0; cc < 8; ++cc)
                    ac2[rr][cc] = fmaf(xf[rr], wf[cc], ac2[rr][cc]);
        }
    }
    __syncthreads();
    enc_merge(red, ac2, w, rg, cg);

    if (w == 0) {
        float b2v[8];
        *(float4*)&b2v[0] = *(const float4*)(b2 + cg * 8);
        *(float4*)&b2v[4] = *(const float4*)(b2 + cg * 8 + 4);
#pragma unroll
        for (int rr = 0; rr < 8; ++rr) {
            int i = rg * 8 + rr;
            size_t base = (size_t)(r0 + i) * LD + cg * 8;
            float zv[8];
            unsigned short hh[8], ll[8];
#pragma unroll
            for (int cc = 0; cc < 8; ++cc) {
                zv[cc] = ac2[rr][cc] + b2v[cc];
                unsigned short hb = f2bf(zv[cc]);
                hh[cc] = hb;
                ll[cc] = f2bf(zv[cc] - bf2f(hb));
            }
            *(float4*)(zOut + base) = *(const float4*)&zv[0];
            *(float4*)(zOut + base + 4) = *(const float4*)&zv[4];
            *(short8*)(zh + base) = *(const short8*)hh;
            *(short8*)(zl + base) = *(const short8*)ll;
        }
    }
}

// ---------------------------------------------------------------------------
// K2: MFMA split-bf16 screen (round-9 proven: slim tracker, 3-deep prefetch).
// ---------------------------------------------------------------------------
#define K2_LOAD(P, t) do {                                                  \
    const unsigned short* ph_ = ehp + (size_t)(t) * 16 * LD;                \
    const unsigned short* pl_ = elp + (size_t)(t) * 16 * LD;                \
    P##a0 = *(const short8*)(ph_);                                          \
    P##a1 = *(const short8*)(ph_ + 32);                                     \
    P##a2 = *(const short8*)(pl_);                                          \
    P##a3 = *(const short8*)(pl_ + 32);                                     \
    P##e2 = *(const f32x4*)(e2q + cbase + (t) * 16 + hi * 4);               \
} while (0)

#define K2_COMP(P, t) do {                                                  \
    f32x4 acc_[4];                                                          \
    _Pragma("unroll")                                                       \
    for (int g = 0; g < 4; ++g) {                                           \
        f32x4 c_;                                                           \
        c_ = __builtin_amdgcn_mfma_f32_16x16x32_bf16(P##a0, bh[g][0], P##e2, 0, 0, 0); \
        c_ = __builtin_amdgcn_mfma_f32_16x16x32_bf16(P##a1, bh[g][1], c_, 0, 0, 0);    \
        c_ = __builtin_amdgcn_mfma_f32_16x16x32_bf16(P##a2, bh[g][0], c_, 0, 0, 0);    \
        c_ = __builtin_amdgcn_mfma_f32_16x16x32_bf16(P##a3, bh[g][1], c_, 0, 0, 0);    \
        c_ = __builtin_amdgcn_mfma_f32_16x16x32_bf16(P##a0, bl[g][0], c_, 0, 0, 0);    \
        c_ = __builtin_amdgcn_mfma_f32_16x16x32_bf16(P##a1, bl[g][1], c_, 0, 0, 0);    \
        acc_[g] = c_;                                                       \
    }                                                                       \
    _Pragma("unroll")                                                       \
    for (int g = 0; g < 4; ++g) {                                           \
        float m_ = fmaxf(fmaxf(acc_[g][0], acc_[g][1]),                     \
                         fmaxf(acc_[g][2], acc_[g][3]));                    \
        bool win_ = (m_ > bb[g]);                                           \
        qv[g] = win_ ? acc_[g] : qv[g];                                     \
        tt[g] = win_ ? (t) : tt[g];                                         \
        b2v[g] = fmaxf(b2v[g], fminf(bb[g], m_));                           \
        bb[g] = fmaxf(bb[g], m_);                                           \
    }                                                                       \
} while (0)

__global__ __launch_bounds__(256, 2) void k2_mfma(const unsigned short* __restrict__ zh,
                                                  const unsigned short* __restrict__ zl,
                                                  const unsigned short* __restrict__ eh,
                                                  const unsigned short* __restrict__ el,
                                                  const float* __restrict__ e2q,
                                                  int* __restrict__ idx,
                                                  int* __restrict__ list,
                                                  int* __restrict__ count) {
    int tid  = threadIdx.x;
    int lane = tid & 63;
    int w    = tid >> 6;
    int rb   = blockIdx.x * 64;
    int lo   = lane & 15;
    int hi   = lane >> 4;

    short8 bh[4][2], bl[4][2];
#pragma unroll
    for (int g = 0; g < 4; ++g) {
        size_t zo = (size_t)(rb + g * 16 + lo) * LD + hi * 8;
        bh[g][0] = *(const short8*)(zh + zo);
        bh[g][1] = *(const short8*)(zh + zo + 32);
        bl[g][0] = *(const short8*)(zl + zo);
        bl[g][1] = *(const short8*)(zl + zo + 32);
    }

    float bb[4], b2v[4];
    f32x4 qv[4];
    int   tt[4];
#pragma unroll
    for (int g = 0; g < 4; ++g) {
        bb[g] = -3.0e38f; b2v[g] = -3.0e38f; tt[g] = 0;
        qv[g][0] = qv[g][1] = qv[g][2] = qv[g][3] = -3.0e38f;
    }

    const int cbase = w * (NEMB / 4);
    const unsigned short* ehp = eh + (size_t)(cbase + lo) * LD + hi * 8;
    const unsigned short* elp = el + (size_t)(cbase + lo) * LD + hi * 8;

    short8 Aa0, Aa1, Aa2, Aa3; f32x4 Ae2;
    short8 Ba0, Ba1, Ba2, Ba3; f32x4 Be2;
    short8 Ca0, Ca1, Ca2, Ca3; f32x4 Ce2;

    K2_LOAD(A, 0);
    K2_LOAD(B, 1);
    K2_LOAD(C, 2);

    for (int tb = 0; tb < 27; tb += 3) {
        K2_COMP(A, tb);     K2_LOAD(A, tb + 3);
        K2_COMP(B, tb + 1); K2_LOAD(B, tb + 4);
        K2_COMP(C, tb + 2); K2_LOAD(C, tb + 5);
    }
    K2_COMP(A, 27); K2_LOAD(A, 30);
    K2_COMP(B, 28); K2_LOAD(B, 31);
    K2_COMP(C, 29);
    K2_COMP(A, 30);
    K2_COMP(B, 31);

    float ss[4];
    int   ii[4];
#pragma unroll
    for (int g = 0; g < 4; ++g) {
        float s0 = qv[g][0], s1 = qv[g][1], s2 = qv[g][2], s3 = qv[g][3];
        float M01 = fmaxf(s0, s1), L01 = fminf(s0, s1);
        float M23 = fmaxf(s2, s3), L23 = fminf(s2, s3);
        int   d01 = (s1 > s0) ? 1 : 0;
        int   d23 = (s3 > s2) ? 3 : 2;
        bool  cp  = (M23 > M01);
        float within2 = fmaxf(fminf(M01, M23), cp ? L23 : L01);
        int   dd  = cp ? d23 : d01;
        ii[g] = cbase + tt[g] * 16 + hi * 4 + dd;
        ss[g] = fmaxf(b2v[g], within2);
    }

#pragma unroll
    for (int off = 16; off <= 32; off <<= 1) {
#pragma unroll
        for (int g = 0; g < 4; ++g) {
            float ob = __shfl_xor(bb[g], off);
            float os = __shfl_xor(ss[g], off);
            int   oi = __shfl_xor(ii[g], off);
            ss[g] = fmaxf(fmaxf(fminf(bb[g], ob), os), ss[g]);
            ii[g] = (ob > bb[g]) ? oi : ii[g];
            bb[g] = fmaxf(bb[g], ob);
        }
    }

    __shared__ float Lb[4][64];
    __shared__ float Ls[4][64];
    __shared__ int   Li[4][64];
    if (lane < 16) {
#pragma unroll
        for (int g = 0; g < 4; ++g) {
            Lb[w][g * 16 + lane] = bb[g];
            Ls[w][g * 16 + lane] = ss[g];
            Li[w][g * 16 + lane] = ii[g];
        }
    }
    __syncthreads();

    if (tid < 64) {
        float B = Lb[0][tid], S = Ls[0][tid];
        int   I = Li[0][tid];
#pragma unroll
        for (int w2 = 1; w2 < 4; ++w2) {
            float ob = Lb[w2][tid], os = Ls[w2][tid];
            int   oi = Li[w2][tid];
            S = fmaxf(fmaxf(fminf(B, ob), os), S);
            I = (ob > B) ? oi : I;
            B = fmaxf(B, ob);
        }
        idx[rb + tid] = I;
        if (B - S < REFINE_THR_Q) {
            int p = atomicAdd(count, 1);
            list[p] = rb + tid;
        }
    }
}

// ---------------------------------------------------------------------------
// K3: exact f64 rescan of flagged near-tie rows.
// ---------------------------------------------------------------------------
__global__ __launch_bounds__(256) void k3_refine(const float* __restrict__ z,
                                                 const float* __restrict__ emb,
                                                 const int* __restrict__ count,
                                                 const int* __restrict__ list,
                                                 int* __restrict__ idx) {
    __shared__ double sv[256];
    __shared__ int    sx[256];
    int tid = threadIdx.x;
    int n = *count;
    for (int g = blockIdx.x; g < n; g += gridDim.x) {
        int row = list[g];
        const float4* zr4 = (const float4*)(z + (size_t)row * LD);
        float4 zv[16];
#pragma unroll
        for (int q = 0; q < 16; ++q) zv[q] = zr4[q];

        double best = 1.0e300;
        int bi = NEMB;
#pragma unroll 2
        for (int c = 0; c < 8; ++c) {
            int k = tid * 8 + c;
            const float4* er = (const float4*)(emb + (size_t)k * LD);
            double d0 = 0.0, d1 = 0.0, d2 = 0.0, d3 = 0.0;
#pragma unroll
            for (int q = 0; q < 16; ++q) {
                float4 e4 = er[q];
                double tx = (double)zv[q].x - (double)e4.x;
                double ty = (double)zv[q].y - (double)e4.y;
                double tz = (double)zv[q].z - (double)e4.z;
                double tw = (double)zv[q].w - (double)e4.w;
                d0 += tx * tx; d1 += ty * ty; d2 += tz * tz; d3 += tw * tw;
            }
            double d = (d0 + d1) + (d2 + d3);
            if (d < best) { best = d; bi = k; }
        }
        sv[tid] = best; sx[tid] = bi;
        __syncthreads();
        for (int s = 128; s > 0; s >>= 1) {
            if (tid < s) {
                if (sv[tid + s] < sv[tid] ||
                    (sv[tid + s] == sv[tid] && sx[tid + s] < sx[tid])) {
                    sv[tid] = sv[tid + s]; sx[tid] = sx[tid + s];
                }
            }
            __syncthreads();
        }
        if (tid == 0) idx[row] = sx[0];
        __syncthreads();
    }
}

// ---------------------------------------------------------------------------
// DEC v3 (MFMA split-bf16, 3 terms) — round-11 proven.
// ---------------------------------------------------------------------------
__global__ __launch_bounds__(256, 2) void k_dec(const int* __restrict__ idx,
                                                const float* __restrict__ emb,
                                                const unsigned short* __restrict__ w1h,
                                                const unsigned short* __restrict__ w1l,
                                                const float* __restrict__ b1,
                                                const unsigned short* __restrict__ w2h,
                                                const unsigned short* __restrict__ w2l,
                                                const float* __restrict__ b2,
                                                float* __restrict__ xrec,
                                                float* __restrict__ zq) {
    __shared__ float hds[4][16 * 68];
    int tid  = threadIdx.x;
    int lane = tid & 63;
    int w    = tid >> 6;
    int lo   = lane & 15;
    int hi   = lane >> 4;
    int rb   = blockIdx.x * 64 + w * 16;
    int row  = rb + lo;
    int ix   = idx[row];

    short8 zah[2], zal[2];
    {
        const float* er  = emb + (size_t)ix * LD + hi * 8;
        float* zqr = zq + (size_t)row * LD + hi * 8;
#pragma unroll
        for (int kt = 0; kt < 2; ++kt) {
            float4 a = *(const float4*)(er + kt * 32);
            float4 b = *(const float4*)(er + kt * 32 + 4);
            *(float4*)(zqr + kt * 32) = a;
            *(float4*)(zqr + kt * 32 + 4) = b;
            float v[8] = {a.x, a.y, a.z, a.w, b.x, b.y, b.z, b.w};
            unsigned short hh[8], ll[8];
#pragma unroll
            for (int q = 0; q < 8; ++q) {
                unsigned short hb = f2bf(v[q]);
                hh[q] = hb;
                ll[q] = f2bf(v[q] - bf2f(hb));
            }
            zah[kt] = *(short8*)hh;
            zal[kt] = *(short8*)ll;
        }
    }

#pragma unroll
    for (int jt = 0; jt < 4; ++jt) {
        float bj = b1[jt * 16 + lo];
        f32x4 c = {bj, bj, bj, bj};
#pragma unroll
        for (int kt = 0; kt < 2; ++kt) {
            short8 bh8 = *(const short8*)(w1h + (jt * 16 + lo) * LD + kt * 32 + hi * 8);
            short8 bl8 = *(const short8*)(w1l + (jt * 16 + lo) * LD + kt * 32 + hi * 8);
            c = __builtin_amdgcn_mfma_f32_16x16x32_bf16(zah[kt], bh8, c, 0, 0, 0);
            c = __builtin_amdgcn_mfma_f32_16x16x32_bf16(zah[kt], bl8, c, 0, 0, 0);
            c = __builtin_amdgcn_mfma_f32_16x16x32_bf16(zal[kt], bh8, c, 0, 0, 0);
        }
#pragma unroll
        for (int r = 0; r < 4; ++r)
            hds[w][(hi * 4 + r) * 68 + jt * 16 + lo] = fmaxf(c[r], 0.f);
    }
    __syncthreads();

    short8 hah[2], hal[2];
#pragma unroll
    for (int kt = 0; kt < 2; ++kt) {
        float4 a = *(const float4*)&hds[w][lo * 68 + kt * 32 + hi * 8];
        float4 b = *(const float4*)&hds[w][lo * 68 + kt * 32 + hi * 8 + 4];
        float v[8] = {a.x, a.y, a.z, a.w, b.x, b.y, b.z, b.w};
        unsigned short hh[8], ll[8];
#pragma unroll
        for (int q = 0; q < 8; ++q) {
            unsigned short hb = f2bf(v[q]);
            hh[q] = hb;
            ll[q] = f2bf(v[q] - bf2f(hb));
        }
        hah[kt] = *(short8*)hh;
        hal[kt] = *(short8*)ll;
    }

    for (int jt = 0; jt < 16; ++jt) {
        float bj = b2[jt * 16 + lo];
        f32x4 c = {bj, bj, bj, bj};
#pragma unroll
        for (int kt = 0; kt < 2; ++kt) {
            short8 bh8 = *(const short8*)(w2h + (jt * 16 + lo) * LD + kt * 32 + hi * 8);
            short8 bl8 = *(const short8*)(w2l + (jt * 16 + lo) * LD + kt * 32 + hi * 8);
            c = __builtin_amdgcn_mfma_f32_16x16x32_bf16(hah[kt], bh8, c, 0, 0, 0);
            c = __builtin_amdgcn_mfma_f32_16x16x32_bf16(hah[kt], bl8, c, 0, 0, 0);
            c = __builtin_amdgcn_mfma_f32_16x16x32_bf16(hal[kt], bh8, c, 0, 0, 0);
        }
#pragma unroll
        for (int r = 0; r < 4; ++r)
            xrec[(size_t)(rb + hi * 4 + r) * SD + jt * 16 + lo] = c[r];
    }
}

// ---------------------------------------------------------------------------
extern "C" void kernel_launch(void* const* d_in, const int* in_sizes, int n_in,
                              void* d_out, int out_size, void* d_ws, size_t ws_size,
                              hipStream_t stream) {
    const float* x   = (const float*)d_in[0];
    const float* ew1 = (const float*)d_in[1];
    const float* eb1 = (const float*)d_in[2];
    const float* ew2 = (const float*)d_in[3];
    const float* eb2 = (const float*)d_in[4];
    const float* emb = (const float*)d_in[5];
    const float* dw1 = (const float*)d_in[6];
    const float* db1 = (const float*)d_in[7];
    const float* dw2 = (const float*)d_in[8];
    const float* db2 = (const float*)d_in[9];

    float* out  = (float*)d_out;
    float* xrec = out;                               // [B,256] (written LAST)
    float* zE   = out + (size_t)BATCH * SD;          // [B,64]
    float* zQ   = zE + (size_t)BATCH * LD;           // [B,64]

    char* xb = (char*)xrec;
    unsigned short* zh  = (unsigned short*)xb;                        // 4 MB
    unsigned short* zl  = (unsigned short*)(xb + (4u << 20));         // 4 MB
    unsigned short* eh  = (unsigned short*)(xb + (8u << 20));         // 256 KB
    unsigned short* el  = (unsigned short*)(xb + (8u << 20) + (NEMB * LD * 2)); // 256 KB
    float*          e2q = (float*)(xb + (9u << 20));                  // 8 KB

    char* ws = (char*)d_ws;
    int*  count = (int*)ws;                                     // 4 B
    int*  idxA  = (int*)(ws + 16384);                           // 128 KB
    int*  list  = (int*)(ws + 147456);                          // 128 KB
    unsigned short* w1h = (unsigned short*)(ws + 278528);       // 8 KB
    unsigned short* w1l = (unsigned short*)(ws + 286720);       // 8 KB
    unsigned short* w2h = (unsigned short*)(ws + 294912);       // 32 KB
    unsigned short* w2l = (unsigned short*)(ws + 327680);       // 32 KB

    hipLaunchKernelGGL(k0_prep,    dim3(NEMB / 256), dim3(256), 0, stream, emb, e2q, eh, el, count);
    hipLaunchKernelGGL(k0b_wsplit, dim3(80),         dim3(256), 0, stream, dw1, dw2, w1h, w1l, w2h, w2l);
    hipLaunchKernelGGL(k_enc,      dim3(BATCH / 64), dim3(512), 0, stream, x, ew1, eb1, ew2, eb2, zE, zh, zl);
    hipLaunchKernelGGL(k2_mfma,    dim3(BATCH / 64), dim3(256), 0, stream, zh, zl, eh, el, e2q, idxA, list, count);
    hipLaunchKernelGGL(k3_refine,  dim3(128),        dim3(256), 0, stream, zE, emb, count, list, idxA);
    hipLaunchKernelGGL(k_dec,      dim3(BATCH / 64), dim3(256), 0, stream, idxA, emb, w1h, w1l, db1, w2h, w2l, db2, xrec, zQ);
}

// Round 13
// 131.801 us; speedup vs baseline: 1.0038x; 1.0038x over previous
//
#include <hip/hip_runtime.h>

#define BATCH   32768
#define SD      256
#define LD      64
#define HDIM    64
#define NEMB    2048
#define REFINE_THR_Q 5e-4f   // gap in q-units; s-gap = 2*q-gap -> 1e-3 effective

typedef short  short8 __attribute__((ext_vector_type(8)));
typedef float  f32x4  __attribute__((ext_vector_type(4)));

__device__ __forceinline__ unsigned short f2bf(float f) {
    unsigned int u = __float_as_uint(f);
    u = (u + 0x7FFFu + ((u >> 16) & 1u)) >> 16;
    return (unsigned short)u;
}
__device__ __forceinline__ float bf2f(unsigned short h) {
    return __uint_as_float(((unsigned int)h) << 16);
}

// ---------------------------------------------------------------------------
// K0: e2q[k] = -0.5*||emb[k]||^2, bf16 split eh/el, zero refine counter.
// ---------------------------------------------------------------------------
__global__ __launch_bounds__(256) void k0_prep(const float* __restrict__ emb,
                                               float* __restrict__ e2q,
                                               unsigned short* __restrict__ eh,
                                               unsigned short* __restrict__ el,
                                               int* __restrict__ count) {
    int k = blockIdx.x * 256 + threadIdx.x;
    if (k == 0) *count = 0;
    const float* er = emb + (size_t)k * LD;
    unsigned short hrow[LD], lrow[LD];
    float s = 0.f;
#pragma unroll
    for (int q = 0; q < LD; ++q) {
        float v = er[q];
        s += v * v;
        unsigned short h = f2bf(v);
        hrow[q] = h;
        lrow[q] = f2bf(v - bf2f(h));
    }
    e2q[k] = -0.5f * s;
    short8* dh = (short8*)(eh + (size_t)k * LD);
    short8* dl = (short8*)(el + (size_t)k * LD);
#pragma unroll
    for (int q = 0; q < 8; ++q) {
        dh[q] = *(short8*)&hrow[q * 8];
        dl[q] = *(short8*)&lrow[q * 8];
    }
}

// ---------------------------------------------------------------------------
// K0b: split decoder weights to bf16 h/l, TRANSPOSED to [j][k] for B-frags.
// ---------------------------------------------------------------------------
__global__ __launch_bounds__(256) void k0b_wsplit(const float* __restrict__ w1,
                                                  const float* __restrict__ w2,
                                                  unsigned short* __restrict__ w1h,
                                                  unsigned short* __restrict__ w1l,
                                                  unsigned short* __restrict__ w2h,
                                                  unsigned short* __restrict__ w2l) {
    int b = blockIdx.x;
    int t = threadIdx.x;
    if (b < 16) {
        int e = b * 256 + t;
        int j = e >> 6, k = e & 63;
        float v = w1[k * HDIM + j];
        unsigned short h = f2bf(v);
        w1h[e] = h; w1l[e] = f2bf(v - bf2f(h));
    } else {
        int e = (b - 16) * 256 + t;
        int j = e >> 6, k = e & 63;
        float v = w2[k * SD + j];
        unsigned short h = f2bf(v);
        w2h[e] = h; w2l[e] = f2bf(v - bf2f(h));
    }
}

// ---------------------------------------------------------------------------
// ENC v4: 8x8 outer-product register tiling, f32 exact, CONFLICT-FIXED.
// xT block-swizzled: (k,r) -> k*64 + ((r>>3 + (k>>2))&7)*8 + (r&7)  (2-way max).
// Merge slices lane-contiguous: red[s][cc][half][lane*4] (coalesced b128).
// 512 thr (8 waves), 64 rows/block, LDS 128KB -> 1 block/CU.
// ---------------------------------------------------------------------------
__device__ __forceinline__ void wr_slice(float* red, int s, float (&a)[8][8],
                                         int lane) {
#pragma unroll
    for (int cc = 0; cc < 8; ++cc) {
        float4 v0 = {a[0][cc], a[1][cc], a[2][cc], a[3][cc]};
        float4 v1 = {a[4][cc], a[5][cc], a[6][cc], a[7][cc]};
        float* p = red + s * 4096 + cc * 512 + lane * 4;
        *(float4*)p = v0;
        *(float4*)(p + 256) = v1;
    }
}
__device__ __forceinline__ void add_slice(float* red, int s, float (&a)[8][8],
                                          int lane) {
#pragma unroll
    for (int cc = 0; cc < 8; ++cc) {
        const float* p = red + s * 4096 + cc * 512 + lane * 4;
        float4 v0 = *(const float4*)p;
        float4 v1 = *(const float4*)(p + 256);
        a[0][cc] += v0.x; a[1][cc] += v0.y; a[2][cc] += v0.z; a[3][cc] += v0.w;
        a[4][cc] += v1.x; a[5][cc] += v1.y; a[6][cc] += v1.z; a[7][cc] += v1.w;
    }
}
__device__ __forceinline__ void enc_merge(float* red, float (&a)[8][8],
                                          int w, int lane) {
    if (w & 1) wr_slice(red, w >> 1, a, lane);
    __syncthreads();
    if (!(w & 1)) add_slice(red, w >> 1, a, lane);
    __syncthreads();
    if (w == 2) wr_slice(red, 0, a, lane);
    if (w == 6) wr_slice(red, 1, a, lane);
    __syncthreads();
    if (w == 0) add_slice(red, 0, a, lane);
    if (w == 4) add_slice(red, 1, a, lane);
    __syncthreads();
    if (w == 4) wr_slice(red, 0, a, lane);
    __syncthreads();
    if (w == 0) add_slice(red, 0, a, lane);
}

__global__ __launch_bounds__(512, 2) void k_enc(const float* __restrict__ x,
                                                const float* __restrict__ w1,
                                                const float* __restrict__ b1,
                                                const float* __restrict__ w2,
                                                const float* __restrict__ b2,
                                                float* __restrict__ zOut,
                                                unsigned short* __restrict__ zh,
                                                unsigned short* __restrict__ zl) {
    __shared__ float smem[32768];      // 128 KB
    float* xT  = smem;                 // swizzled [256][64]  (L1)
    float* w1s = smem + 16384;         // [256][64]           (L1)
    float* red = smem;                 // merge [4][4096] lane-contiguous
    float* w2s = smem + 16384;         // [64][64]            (L2)
    float* hs  = smem + 20480;         // [64][66]            (L2, padded)

    int tid  = threadIdx.x;
    int lane = tid & 63;
    int w    = tid >> 6;
    int rg   = lane & 7;
    int cg   = lane >> 3;
    int r0   = blockIdx.x * 64;

    // stage xT (swizzled transpose) + w1
    {
        int r = tid >> 3, kq = tid & 7;
        int rblk = r >> 3, rin = r & 7;
        const float* xr = x + (size_t)(r0 + r) * SD;
#pragma unroll
        for (int p = 0; p < 8; ++p) {
            int k = p * 32 + kq * 4;
            float4 v = *(const float4*)(xr + k);
            int so = ((rblk + (k >> 2)) & 7) * 8 + rin;
            xT[(k + 0) * 64 + so] = v.x;
            xT[(k + 1) * 64 + so] = v.y;
            xT[(k + 2) * 64 + so] = v.z;
            xT[(k + 3) * 64 + so] = v.w;
        }
        const float4* src = (const float4*)w1;
        float4* dst = (float4*)w1s;
#pragma unroll
        for (int t = 0; t < 8; ++t) dst[tid + 512 * t] = src[tid + 512 * t];
    }
    __syncthreads();

    // ---- L1 k-loop: wave w covers k = w*32 .. w*32+31
    float acc[8][8];
#pragma unroll
    for (int i = 0; i < 8; ++i)
#pragma unroll
        for (int j = 0; j < 8; ++j) acc[i][j] = 0.f;
    {
        int k0 = w * 32;
#pragma unroll 4
        for (int k = k0; k < k0 + 32; ++k) {
            int xo = k * 64 + (((rg + (k >> 2)) & 7) << 3);
            float4 xa = *(const float4*)&xT[xo];
            float4 xb = *(const float4*)&xT[xo + 4];
            float4 wa = *(const float4*)&w1s[k * 64 + cg * 8];
            float4 wb = *(const float4*)&w1s[k * 64 + cg * 8 + 4];
            float xf[8] = {xa.x, xa.y, xa.z, xa.w, xb.x, xb.y, xb.z, xb.w};
            float wf[8] = {wa.x, wa.y, wa.z, wa.w, wb.x, wb.y, wb.z, wb.w};
#pragma unroll
            for (int rr = 0; rr < 8; ++rr)
#pragma unroll
                for (int cc = 0; cc < 8; ++cc)
                    acc[rr][cc] = fmaf(xf[rr], wf[cc], acc[rr][cc]);
        }
    }
    __syncthreads();                    // xT/w1s dead; red/w2s/hs live next

    // stage w2 (into dead w1s region) while merge starts
    {
        const float4* src = (const float4*)w2;
        float4* dst = (float4*)w2s;
        dst[tid] = src[tid];
        dst[tid + 512] = src[tid + 512];
    }
    enc_merge(red, acc, w, lane);

    // wave 0 finalizes h = relu(acc + b1), stores TRANSPOSED hs[j][i]
    if (w == 0) {
        float b1v[8];
        *(float4*)&b1v[0] = *(const float4*)(b1 + cg * 8);
        *(float4*)&b1v[4] = *(const float4*)(b1 + cg * 8 + 4);
#pragma unroll
        for (int cc = 0; cc < 8; ++cc) {
            int j = cg * 8 + cc;
            float4 h0 = {fmaxf(acc[0][cc] + b1v[cc], 0.f),
                         fmaxf(acc[1][cc] + b1v[cc], 0.f),
                         fmaxf(acc[2][cc] + b1v[cc], 0.f),
                         fmaxf(acc[3][cc] + b1v[cc], 0.f)};
            float4 h1 = {fmaxf(acc[4][cc] + b1v[cc], 0.f),
                         fmaxf(acc[5][cc] + b1v[cc], 0.f),
                         fmaxf(acc[6][cc] + b1v[cc], 0.f),
                         fmaxf(acc[7][cc] + b1v[cc], 0.f)};
            *(float4*)&hs[j * 66 + rg * 8] = h0;
            *(float4*)&hs[j * 66 + rg * 8 + 4] = h1;
        }
    }
    __syncthreads();

    // ---- L2 k-loop: wave w covers k2 = w*8 .. w*8+7
    float ac2[8][8];
#pragma unroll
    for (int i = 0; i < 8; ++i)
#pragma unroll
        for (int j = 0; j < 8; ++j) ac2[i][j] = 0.f;
    {
        int q0 = w * 8;
#pragma unroll
        for (int k2 = q0; k2 < q0 + 8; ++k2) {
            float4 xa = *(const float4*)&hs[k2 * 66 + rg * 8];
            float4 xb = *(const float4*)&hs[k2 * 66 + rg * 8 + 4];
            float4 wa = *(const float4*)&w2s[k2 * 64 + cg * 8];
            float4 wb = *(const float4*)&w2s[k2 * 64 + cg * 8 + 4];
            float xf[8] = {xa.x, xa.y, xa.z, xa.w, xb.x, xb.y, xb.z, xb.w};
            float wf[8] = {wa.x, wa.y, wa.z, wa.w, wb.x, wb.y, wb.z, wb.w};
#pragma unroll
            for (int rr = 0; rr < 8; ++rr)
#pragma unroll
                for (int cc = 0; cc < 8; ++cc)
                    ac2[rr][cc] = fmaf(xf[rr], wf[cc], ac2[rr][cc]);
        }
    }
    __syncthreads();
    enc_merge(red, ac2, w, lane);

    if (w == 0) {
        float b2v[8];
        *(float4*)&b2v[0] = *(const float4*)(b2 + cg * 8);
        *(float4*)&b2v[4] = *(const float4*)(b2 + cg * 8 + 4);
#pragma unroll
        for (int rr = 0; rr < 8; ++rr) {
            int i = rg * 8 + rr;
            size_t base = (size_t)(r0 + i) * LD + cg * 8;
            float zv[8];
            unsigned short hh[8], ll[8];
#pragma unroll
            for (int cc = 0; cc < 8; ++cc) {
                zv[cc] = ac2[rr][cc] + b2v[cc];
                unsigned short hb = f2bf(zv[cc]);
                hh[cc] = hb;
                ll[cc] = f2bf(zv[cc] - bf2f(hb));
            }
            *(float4*)(zOut + base) = *(const float4*)&zv[0];
            *(float4*)(zOut + base + 4) = *(const float4*)&zv[4];
            *(short8*)(zh + base) = *(const short8*)hh;
            *(short8*)(zl + base) = *(const short8*)ll;
        }
    }
}

// ---------------------------------------------------------------------------
// K2: MFMA split-bf16 screen (round-9 proven: slim tracker, 3-deep prefetch).
// ---------------------------------------------------------------------------
#define K2_LOAD(P, t) do {                                                  \
    const unsigned short* ph_ = ehp + (size_t)(t) * 16 * LD;                \
    const unsigned short* pl_ = elp + (size_t)(t) * 16 * LD;                \
    P##a0 = *(const short8*)(ph_);                                          \
    P##a1 = *(const short8*)(ph_ + 32);                                     \
    P##a2 = *(const short8*)(pl_);                                          \
    P##a3 = *(const short8*)(pl_ + 32);                                     \
    P##e2 = *(const f32x4*)(e2q + cbase + (t) * 16 + hi * 4);               \
} while (0)

#define K2_COMP(P, t) do {                                                  \
    f32x4 acc_[4];                                                          \
    _Pragma("unroll")                                                       \
    for (int g = 0; g < 4; ++g) {                                           \
        f32x4 c_;                                                           \
        c_ = __builtin_amdgcn_mfma_f32_16x16x32_bf16(P##a0, bh[g][0], P##e2, 0, 0, 0); \
        c_ = __builtin_amdgcn_mfma_f32_16x16x32_bf16(P##a1, bh[g][1], c_, 0, 0, 0);    \
        c_ = __builtin_amdgcn_mfma_f32_16x16x32_bf16(P##a2, bh[g][0], c_, 0, 0, 0);    \
        c_ = __builtin_amdgcn_mfma_f32_16x16x32_bf16(P##a3, bh[g][1], c_, 0, 0, 0);    \
        c_ = __builtin_amdgcn_mfma_f32_16x16x32_bf16(P##a0, bl[g][0], c_, 0, 0, 0);    \
        c_ = __builtin_amdgcn_mfma_f32_16x16x32_bf16(P##a1, bl[g][1], c_, 0, 0, 0);    \
        acc_[g] = c_;                                                       \
    }                                                                       \
    _Pragma("unroll")                                                       \
    for (int g = 0; g < 4; ++g) {                                           \
        float m_ = fmaxf(fmaxf(acc_[g][0], acc_[g][1]),                     \
                         fmaxf(acc_[g][2], acc_[g][3]));                    \
        bool win_ = (m_ > bb[g]);                                           \
        qv[g] = win_ ? acc_[g] : qv[g];                                     \
        tt[g] = win_ ? (t) : tt[g];                                         \
        b2v[g] = fmaxf(b2v[g], fminf(bb[g], m_));                           \
        bb[g] = fmaxf(bb[g], m_);                                           \
    }                                                                       \
} while (0)

__global__ __launch_bounds__(256, 2) void k2_mfma(const unsigned short* __restrict__ zh,
                                                  const unsigned short* __restrict__ zl,
                                                  const unsigned short* __restrict__ eh,
                                                  const unsigned short* __restrict__ el,
                                                  const float* __restrict__ e2q,
                                                  int* __restrict__ idx,
                                                  int* __restrict__ list,
                                                  int* __restrict__ count) {
    int tid  = threadIdx.x;
    int lane = tid & 63;
    int w    = tid >> 6;
    int rb   = blockIdx.x * 64;
    int lo   = lane & 15;
    int hi   = lane >> 4;

    short8 bh[4][2], bl[4][2];
#pragma unroll
    for (int g = 0; g < 4; ++g) {
        size_t zo = (size_t)(rb + g * 16 + lo) * LD + hi * 8;
        bh[g][0] = *(const short8*)(zh + zo);
        bh[g][1] = *(const short8*)(zh + zo + 32);
        bl[g][0] = *(const short8*)(zl + zo);
        bl[g][1] = *(const short8*)(zl + zo + 32);
    }

    float bb[4], b2v[4];
    f32x4 qv[4];
    int   tt[4];
#pragma unroll
    for (int g = 0; g < 4; ++g) {
        bb[g] = -3.0e38f; b2v[g] = -3.0e38f; tt[g] = 0;
        qv[g][0] = qv[g][1] = qv[g][2] = qv[g][3] = -3.0e38f;
    }

    const int cbase = w * (NEMB / 4);
    const unsigned short* ehp = eh + (size_t)(cbase + lo) * LD + hi * 8;
    const unsigned short* elp = el + (size_t)(cbase + lo) * LD + hi * 8;

    short8 Aa0, Aa1, Aa2, Aa3; f32x4 Ae2;
    short8 Ba0, Ba1, Ba2, Ba3; f32x4 Be2;
    short8 Ca0, Ca1, Ca2, Ca3; f32x4 Ce2;

    K2_LOAD(A, 0);
    K2_LOAD(B, 1);
    K2_LOAD(C, 2);

    for (int tb = 0; tb < 27; tb += 3) {
        K2_COMP(A, tb);     K2_LOAD(A, tb + 3);
        K2_COMP(B, tb + 1); K2_LOAD(B, tb + 4);
        K2_COMP(C, tb + 2); K2_LOAD(C, tb + 5);
    }
    K2_COMP(A, 27); K2_LOAD(A, 30);
    K2_COMP(B, 28); K2_LOAD(B, 31);
    K2_COMP(C, 29);
    K2_COMP(A, 30);
    K2_COMP(B, 31);

    float ss[4];
    int   ii[4];
#pragma unroll
    for (int g = 0; g < 4; ++g) {
        float s0 = qv[g][0], s1 = qv[g][1], s2 = qv[g][2], s3 = qv[g][3];
        float M01 = fmaxf(s0, s1), L01 = fminf(s0, s1);
        float M23 = fmaxf(s2, s3), L23 = fminf(s2, s3);
        int   d01 = (s1 > s0) ? 1 : 0;
        int   d23 = (s3 > s2) ? 3 : 2;
        bool  cp  = (M23 > M01);
        float within2 = fmaxf(fminf(M01, M23), cp ? L23 : L01);
        int   dd  = cp ? d23 : d01;
        ii[g] = cbase + tt[g] * 16 + hi * 4 + dd;
        ss[g] = fmaxf(b2v[g], within2);
    }

#pragma unroll
    for (int off = 16; off <= 32; off <<= 1) {
#pragma unroll
        for (int g = 0; g < 4; ++g) {
            float ob = __shfl_xor(bb[g], off);
            float os = __shfl_xor(ss[g], off);
            int   oi = __shfl_xor(ii[g], off);
            ss[g] = fmaxf(fmaxf(fminf(bb[g], ob), os), ss[g]);
            ii[g] = (ob > bb[g]) ? oi : ii[g];
            bb[g] = fmaxf(bb[g], ob);
        }
    }

    __shared__ float Lb[4][64];
    __shared__ float Ls[4][64];
    __shared__ int   Li[4][64];
    if (lane < 16) {
#pragma unroll
        for (int g = 0; g < 4; ++g) {
            Lb[w][g * 16 + lane] = bb[g];
            Ls[w][g * 16 + lane] = ss[g];
            Li[w][g * 16 + lane] = ii[g];
        }
    }
    __syncthreads();

    if (tid < 64) {
        float B = Lb[0][tid], S = Ls[0][tid];
        int   I = Li[0][tid];
#pragma unroll
        for (int w2 = 1; w2 < 4; ++w2) {
            float ob = Lb[w2][tid], os = Ls[w2][tid];
            int   oi = Li[w2][tid];
            S = fmaxf(fmaxf(fminf(B, ob), os), S);
            I = (ob > B) ? oi : I;
            B = fmaxf(B, ob);
        }
        idx[rb + tid] = I;
        if (B - S < REFINE_THR_Q) {
            int p = atomicAdd(count, 1);
            list[p] = rb + tid;
        }
    }
}

// ---------------------------------------------------------------------------
// K3: exact f64 rescan of flagged near-tie rows.
// ---------------------------------------------------------------------------
__global__ __launch_bounds__(256) void k3_refine(const float* __restrict__ z,
                                                 const float* __restrict__ emb,
                                                 const int* __restrict__ count,
                                                 const int* __restrict__ list,
                                                 int* __restrict__ idx) {
    __shared__ double sv[256];
    __shared__ int    sx[256];
    int tid = threadIdx.x;
    int n = *count;
    for (int g = blockIdx.x; g < n; g += gridDim.x) {
        int row = list[g];
        const float4* zr4 = (const float4*)(z + (size_t)row * LD);
        float4 zv[16];
#pragma unroll
        for (int q = 0; q < 16; ++q) zv[q] = zr4[q];

        double best = 1.0e300;
        int bi = NEMB;
#pragma unroll 2
        for (int c = 0; c < 8; ++c) {
            int k = tid * 8 + c;
            const float4* er = (const float4*)(emb + (size_t)k * LD);
            double d0 = 0.0, d1 = 0.0, d2 = 0.0, d3 = 0.0;
#pragma unroll
            for (int q = 0; q < 16; ++q) {
                float4 e4 = er[q];
                double tx = (double)zv[q].x - (double)e4.x;
                double ty = (double)zv[q].y - (double)e4.y;
                double tz = (double)zv[q].z - (double)e4.z;
                double tw = (double)zv[q].w - (double)e4.w;
                d0 += tx * tx; d1 += ty * ty; d2 += tz * tz; d3 += tw * tw;
            }
            double d = (d0 + d1) + (d2 + d3);
            if (d < best) { best = d; bi = k; }
        }
        sv[tid] = best; sx[tid] = bi;
        __syncthreads();
        for (int s = 128; s > 0; s >>= 1) {
            if (tid < s) {
                if (sv[tid + s] < sv[tid] ||
                    (sv[tid + s] == sv[tid] && sx[tid + s] < sx[tid])) {
                    sv[tid] = sv[tid + s]; sx[tid] = sx[tid + s];
                }
            }
            __syncthreads();
        }
        if (tid == 0) idx[row] = sx[0];
        __syncthreads();
    }
}

// ---------------------------------------------------------------------------
// DEC v3 (MFMA split-bf16, 3 terms) — round-11 proven.
// ---------------------------------------------------------------------------
__global__ __launch_bounds__(256, 2) void k_dec(const int* __restrict__ idx,
                                                const float* __restrict__ emb,
                                                const unsigned short* __restrict__ w1h,
                                                const unsigned short* __restrict__ w1l,
                                                const float* __restrict__ b1,
                                                const unsigned short* __restrict__ w2h,
                                                const unsigned short* __restrict__ w2l,
                                                const float* __restrict__ b2,
                                                float* __restrict__ xrec,
                                                float* __restrict__ zq) {
    __shared__ float hds[4][16 * 68];
    int tid  = threadIdx.x;
    int lane = tid & 63;
    int w    = tid >> 6;
    int lo   = lane & 15;
    int hi   = lane >> 4;
    int rb   = blockIdx.x * 64 + w * 16;
    int row  = rb + lo;
    int ix   = idx[row];

    short8 zah[2], zal[2];
    {
        const float* er  = emb + (size_t)ix * LD + hi * 8;
        float* zqr = zq + (size_t)row * LD + hi * 8;
#pragma unroll
        for (int kt = 0; kt < 2; ++kt) {
            float4 a = *(const float4*)(er + kt * 32);
            float4 b = *(const float4*)(er + kt * 32 + 4);
            *(float4*)(zqr + kt * 32) = a;
            *(float4*)(zqr + kt * 32 + 4) = b;
            float v[8] = {a.x, a.y, a.z, a.w, b.x, b.y, b.z, b.w};
            unsigned short hh[8], ll[8];
#pragma unroll
            for (int q = 0; q < 8; ++q) {
                unsigned short hb = f2bf(v[q]);
                hh[q] = hb;
                ll[q] = f2bf(v[q] - bf2f(hb));
            }
            zah[kt] = *(short8*)hh;
            zal[kt] = *(short8*)ll;
        }
    }

#pragma unroll
    for (int jt = 0; jt < 4; ++jt) {
        float bj = b1[jt * 16 + lo];
        f32x4 c = {bj, bj, bj, bj};
#pragma unroll
        for (int kt = 0; kt < 2; ++kt) {
            short8 bh8 = *(const short8*)(w1h + (jt * 16 + lo) * LD + kt * 32 + hi * 8);
            short8 bl8 = *(const short8*)(w1l + (jt * 16 + lo) * LD + kt * 32 + hi * 8);
            c = __builtin_amdgcn_mfma_f32_16x16x32_bf16(zah[kt], bh8, c, 0, 0, 0);
            c = __builtin_amdgcn_mfma_f32_16x16x32_bf16(zah[kt], bl8, c, 0, 0, 0);
            c = __builtin_amdgcn_mfma_f32_16x16x32_bf16(zal[kt], bh8, c, 0, 0, 0);
        }
#pragma unroll
        for (int r = 0; r < 4; ++r)
            hds[w][(hi * 4 + r) * 68 + jt * 16 + lo] = fmaxf(c[r], 0.f);
    }
    __syncthreads();

    short8 hah[2], hal[2];
#pragma unroll
    for (int kt = 0; kt < 2; ++kt) {
        float4 a = *(const float4*)&hds[w][lo * 68 + kt * 32 + hi * 8];
        float4 b = *(const float4*)&hds[w][lo * 68 + kt * 32 + hi * 8 + 4];
        float v[8] = {a.x, a.y, a.z, a.w, b.x, b.y, b.z, b.w};
        unsigned short hh[8], ll[8];
#pragma unroll
        for (int q = 0; q < 8; ++q) {
            unsigned short hb = f2bf(v[q]);
            hh[q] = hb;
            ll[q] = f2bf(v[q] - bf2f(hb));
        }
        hah[kt] = *(short8*)hh;
        hal[kt] = *(short8*)ll;
    }

    for (int jt = 0; jt < 16; ++jt) {
        float bj = b2[jt * 16 + lo];
        f32x4 c = {bj, bj, bj, bj};
#pragma unroll
        for (int kt = 0; kt < 2; ++kt) {
            short8 bh8 = *(const short8*)(w2h + (jt * 16 + lo) * LD + kt * 32 + hi * 8);
            short8 bl8 = *(const short8*)(w2l + (jt * 16 + lo) * LD + kt * 32 + hi * 8);
            c = __builtin_amdgcn_mfma_f32_16x16x32_bf16(hah[kt], bh8, c, 0, 0, 0);
            c = __builtin_amdgcn_mfma_f32_16x16x32_bf16(hah[kt], bl8, c, 0, 0, 0);
            c = __builtin_amdgcn_mfma_f32_16x16x32_bf16(hal[kt], bh8, c, 0, 0, 0);
        }
#pragma unroll
        for (int r = 0; r < 4; ++r)
            xrec[(size_t)(rb + hi * 4 + r) * SD + jt * 16 + lo] = c[r];
    }
}

// ---------------------------------------------------------------------------
extern "C" void kernel_launch(void* const* d_in, const int* in_sizes, int n_in,
                              void* d_out, int out_size, void* d_ws, size_t ws_size,
                              hipStream_t stream) {
    const float* x   = (const float*)d_in[0];
    const float* ew1 = (const float*)d_in[1];
    const float* eb1 = (const float*)d_in[2];
    const float* ew2 = (const float*)d_in[3];
    const float* eb2 = (const float*)d_in[4];
    const float* emb = (const float*)d_in[5];
    const float* dw1 = (const float*)d_in[6];
    const float* db1 = (const float*)d_in[7];
    const float* dw2 = (const float*)d_in[8];
    const float* db2 = (const float*)d_in[9];

    float* out  = (float*)d_out;
    float* xrec = out;                               // [B,256] (written LAST)
    float* zE   = out + (size_t)BATCH * SD;          // [B,64]
    float* zQ   = zE + (size_t)BATCH * LD;           // [B,64]

    char* xb = (char*)xrec;
    unsigned short* zh  = (unsigned short*)xb;                        // 4 MB
    unsigned short* zl  = (unsigned short*)(xb + (4u << 20));         // 4 MB
    unsigned short* eh  = (unsigned short*)(xb + (8u << 20));         // 256 KB
    unsigned short* el  = (unsigned short*)(xb + (8u << 20) + (NEMB * LD * 2)); // 256 KB
    float*          e2q = (float*)(xb + (9u << 20));                  // 8 KB

    char* ws = (char*)d_ws;
    int*  count = (int*)ws;                                     // 4 B
    int*  idxA  = (int*)(ws + 16384);                           // 128 KB
    int*  list  = (int*)(ws + 147456);                          // 128 KB
    unsigned short* w1h = (unsigned short*)(ws + 278528);       // 8 KB
    unsigned short* w1l = (unsigned short*)(ws + 286720);       // 8 KB
    unsigned short* w2h = (unsigned short*)(ws + 294912);       // 32 KB
    unsigned short* w2l = (unsigned short*)(ws + 327680);       // 32 KB

    hipLaunchKernelGGL(k0_prep,    dim3(NEMB / 256), dim3(256), 0, stream, emb, e2q, eh, el, count);
    hipLaunchKernelGGL(k0b_wsplit, dim3(80),         dim3(256), 0, stream, dw1, dw2, w1h, w1l, w2h, w2l);
    hipLaunchKernelGGL(k_enc,      dim3(BATCH / 64), dim3(512), 0, stream, x, ew1, eb1, ew2, eb2, zE, zh, zl);
    hipLaunchKernelGGL(k2_mfma,    dim3(BATCH / 64), dim3(256), 0, stream, zh, zl, eh, el, e2q, idxA, list, count);
    hipLaunchKernelGGL(k3_refine,  dim3(128),        dim3(256), 0, stream, zE, emb, count, list, idxA);
    hipLaunchKernelGGL(k_dec,      dim3(BATCH / 64), dim3(256), 0, stream, idxA, emb, w1h, w1l, db1, w2h, w2l, db2, xrec, zQ);
}

// Round 14
// 127.326 us; speedup vs baseline: 1.0391x; 1.0351x over previous
//
#include <hip/hip_runtime.h>

#define BATCH   32768
#define SD      256
#define LD      64
#define HDIM    64
#define NEMB    2048
#define REFINE_THR_Q 5e-4f   // gap in q-units; s-gap = 2*q-gap -> 1e-3 effective

typedef short  short8 __attribute__((ext_vector_type(8)));
typedef float  f32x4  __attribute__((ext_vector_type(4)));

__device__ __forceinline__ unsigned short f2bf(float f) {
    unsigned int u = __float_as_uint(f);
    u = (u + 0x7FFFu + ((u >> 16) & 1u)) >> 16;
    return (unsigned short)u;
}
__device__ __forceinline__ float bf2f(unsigned short h) {
    return __uint_as_float(((unsigned int)h) << 16);
}

// ---------------------------------------------------------------------------
// K0 (merged): blocks 0..7   -> e2q + codebook bf16 split (eh/el), counter=0
//              blocks 8..23  -> dec_w1 split transposed [j][k]
//              blocks 24..87 -> dec_w2 split transposed [j][k]
// ---------------------------------------------------------------------------
__global__ __launch_bounds__(256) void k0_all(const float* __restrict__ emb,
                                              const float* __restrict__ dw1,
                                              const float* __restrict__ dw2,
                                              float* __restrict__ e2q,
                                              unsigned short* __restrict__ eh,
                                              unsigned short* __restrict__ el,
                                              unsigned short* __restrict__ w1h,
                                              unsigned short* __restrict__ w1l,
                                              unsigned short* __restrict__ w2h,
                                              unsigned short* __restrict__ w2l,
                                              int* __restrict__ count) {
    int b = blockIdx.x;
    int t = threadIdx.x;
    if (b < 8) {
        int k = b * 256 + t;
        if (k == 0) *count = 0;
        const float* er = emb + (size_t)k * LD;
        unsigned short hrow[LD], lrow[LD];
        float s = 0.f;
#pragma unroll
        for (int q = 0; q < LD; ++q) {
            float v = er[q];
            s += v * v;
            unsigned short h = f2bf(v);
            hrow[q] = h;
            lrow[q] = f2bf(v - bf2f(h));
        }
        e2q[k] = -0.5f * s;
        short8* dh = (short8*)(eh + (size_t)k * LD);
        short8* dl = (short8*)(el + (size_t)k * LD);
#pragma unroll
        for (int q = 0; q < 8; ++q) {
            dh[q] = *(short8*)&hrow[q * 8];
            dl[q] = *(short8*)&lrow[q * 8];
        }
    } else if (b < 24) {
        int e = (b - 8) * 256 + t;      // [j][k]: j = e>>6, k = e&63
        int j = e >> 6, k = e & 63;
        float v = dw1[k * HDIM + j];
        unsigned short h = f2bf(v);
        w1h[e] = h; w1l[e] = f2bf(v - bf2f(h));
    } else {
        int e = (b - 24) * 256 + t;     // [j(256)][k(64)]
        int j = e >> 6, k = e & 63;
        float v = dw2[k * SD + j];
        unsigned short h = f2bf(v);
        w2h[e] = h; w2l[e] = f2bf(v - bf2f(h));
    }
}

// ---------------------------------------------------------------------------
// ENC (round-9/11 proven fused form, measured 44.6-46.5 us x3 rounds):
// z_e = (relu(x@w1+b1))@w2+b2 + bf16 split zh/zl.
// Phase 1: w1 64KB LDS + x dbuf 16KB (coalesced float4, LDS broadcast reads).
// h -> LDS (aliases dead w1s); w2 -> LDS. Phase 2: same pattern.
// 80KB LDS, 512 thr -> 2 blocks/CU, 16 waves/CU.
// ---------------------------------------------------------------------------
__global__ __launch_bounds__(512, 4) void k_enc(const float* __restrict__ x,
                                                const float* __restrict__ w1,
                                                const float* __restrict__ b1,
                                                const float* __restrict__ w2,
                                                const float* __restrict__ b2,
                                                float* __restrict__ zOut,
                                                unsigned short* __restrict__ zh,
                                                unsigned short* __restrict__ zl) {
    __shared__ float smem[20480];          // 80 KB
    float* w1s = smem;
    float* xs  = smem + 16384;
    int tid = threadIdx.x;
    {
        const float4* src = (const float4*)w1;
        float4* dst = (float4*)w1s;
#pragma unroll
        for (int t = 0; t < 8; ++t) dst[tid + 512 * t] = src[tid + 512 * t];
    }
    int r0 = blockIdx.x * 64;
    int sr = tid >> 3;
    int sq = tid & 7;
    const float* xrow = x + (size_t)(r0 + sr) * SD + sq * 4;
    *(float4*)&xs[sr * 32 + sq * 4] = *(const float4*)xrow;
    __syncthreads();

    int lane = tid & 63;
    int w = tid >> 6;
    float acc[8];
#pragma unroll
    for (int r = 0; r < 8; ++r) acc[r] = 0.f;

    for (int c = 0; c < 8; ++c) {
        float4 nv;
        if (c < 7) nv = *(const float4*)(xrow + (c + 1) * 32);
        const float* xb = &xs[(c & 1) * 2048 + (w * 8) * 32];
        int kb = c * 32;
#pragma unroll
        for (int i0 = 0; i0 < 32; i0 += 8) {
            float wf[8];
#pragma unroll
            for (int jj = 0; jj < 8; ++jj) wf[jj] = w1s[(kb + i0 + jj) * HDIM + lane];
#pragma unroll
            for (int r = 0; r < 8; ++r) {
                const float* xr = xb + r * 32 + i0;              // LDS broadcast
                float4 xa = *(const float4*)xr;
                float4 xc = *(const float4*)(xr + 4);
                acc[r] += xa.x * wf[0] + xa.y * wf[1] + xa.z * wf[2] + xa.w * wf[3]
                        + xc.x * wf[4] + xc.y * wf[5] + xc.z * wf[6] + xc.w * wf[7];
            }
        }
        __syncthreads();
        if (c < 7) *(float4*)&xs[((c + 1) & 1) * 2048 + sr * 32 + sq * 4] = nv;
        __syncthreads();
    }

    // phase 1 -> phase 2 handoff: w1s dead; alias h (16KB) + w2 (16KB)
    float* hs  = smem;          // [0,4096)
    float* w2s = smem + 4096;   // [4096,8192)
    float bb1 = b1[lane];
#pragma unroll
    for (int r = 0; r < 8; ++r)
        hs[(w * 8 + r) * 64 + lane] = fmaxf(acc[r] + bb1, 0.f);
    {
        const float4* src = (const float4*)w2;
        float4* dst = (float4*)w2s;
        dst[tid] = src[tid];
        dst[tid + 512] = src[tid + 512];
    }
    __syncthreads();

    const float* hb = &hs[(w * 8) * 64];
    float ac2[8];
#pragma unroll
    for (int r = 0; r < 8; ++r) ac2[r] = 0.f;

    for (int j0 = 0; j0 < HDIM; j0 += 8) {
        float wf[8];
#pragma unroll
        for (int jj = 0; jj < 8; ++jj) wf[jj] = w2s[(j0 + jj) * LD + lane];
#pragma unroll
        for (int r = 0; r < 8; ++r) {
            const float* hr = hb + r * 64 + j0;                  // LDS broadcast
            float4 ha = *(const float4*)hr;
            float4 hc = *(const float4*)(hr + 4);
            ac2[r] += ha.x * wf[0] + ha.y * wf[1] + ha.z * wf[2] + ha.w * wf[3]
                    + hc.x * wf[4] + hc.y * wf[5] + hc.z * wf[6] + hc.w * wf[7];
        }
    }
    float bb2 = b2[lane];
#pragma unroll
    for (int r = 0; r < 8; ++r) {
        float z = ac2[r] + bb2;
        size_t o = (size_t)(r0 + w * 8 + r) * LD + lane;
        zOut[o] = z;
        unsigned short h = f2bf(z);
        zh[o] = h;
        zl[o] = f2bf(z - bf2f(h));
    }
}

// ---------------------------------------------------------------------------
// K2: MFMA split-bf16 screen (proven: slim tracker, 3-deep named prefetch).
// 512 blocks x 256 thr (4 waves), 64 rows/block, wave = quarter codebook.
// ---------------------------------------------------------------------------
#define K2_LOAD(P, t) do {                                                  \
    const unsigned short* ph_ = ehp + (size_t)(t) * 16 * LD;                \
    const unsigned short* pl_ = elp + (size_t)(t) * 16 * LD;                \
    P##a0 = *(const short8*)(ph_);                                          \
    P##a1 = *(const short8*)(ph_ + 32);                                     \
    P##a2 = *(const short8*)(pl_);                                          \
    P##a3 = *(const short8*)(pl_ + 32);                                     \
    P##e2 = *(const f32x4*)(e2q + cbase + (t) * 16 + hi * 4);               \
} while (0)

#define K2_COMP(P, t) do {                                                  \
    f32x4 acc_[4];                                                          \
    _Pragma("unroll")                                                       \
    for (int g = 0; g < 4; ++g) {                                           \
        f32x4 c_;                                                           \
        c_ = __builtin_amdgcn_mfma_f32_16x16x32_bf16(P##a0, bh[g][0], P##e2, 0, 0, 0); \
        c_ = __builtin_amdgcn_mfma_f32_16x16x32_bf16(P##a1, bh[g][1], c_, 0, 0, 0);    \
        c_ = __builtin_amdgcn_mfma_f32_16x16x32_bf16(P##a2, bh[g][0], c_, 0, 0, 0);    \
        c_ = __builtin_amdgcn_mfma_f32_16x16x32_bf16(P##a3, bh[g][1], c_, 0, 0, 0);    \
        c_ = __builtin_amdgcn_mfma_f32_16x16x32_bf16(P##a0, bl[g][0], c_, 0, 0, 0);    \
        c_ = __builtin_amdgcn_mfma_f32_16x16x32_bf16(P##a1, bl[g][1], c_, 0, 0, 0);    \
        acc_[g] = c_;                                                       \
    }                                                                       \
    _Pragma("unroll")                                                       \
    for (int g = 0; g < 4; ++g) {                                           \
        float m_ = fmaxf(fmaxf(acc_[g][0], acc_[g][1]),                     \
                         fmaxf(acc_[g][2], acc_[g][3]));                    \
        bool win_ = (m_ > bb[g]);                                           \
        qv[g] = win_ ? acc_[g] : qv[g];                                     \
        tt[g] = win_ ? (t) : tt[g];                                         \
        b2v[g] = fmaxf(b2v[g], fminf(bb[g], m_));                           \
        bb[g] = fmaxf(bb[g], m_);                                           \
    }                                                                       \
} while (0)

__global__ __launch_bounds__(256, 2) void k2_mfma(const unsigned short* __restrict__ zh,
                                                  const unsigned short* __restrict__ zl,
                                                  const unsigned short* __restrict__ eh,
                                                  const unsigned short* __restrict__ el,
                                                  const float* __restrict__ e2q,
                                                  int* __restrict__ idx,
                                                  int* __restrict__ list,
                                                  int* __restrict__ count) {
    int tid  = threadIdx.x;
    int lane = tid & 63;
    int w    = tid >> 6;
    int rb   = blockIdx.x * 64;
    int lo   = lane & 15;
    int hi   = lane >> 4;

    short8 bh[4][2], bl[4][2];
#pragma unroll
    for (int g = 0; g < 4; ++g) {
        size_t zo = (size_t)(rb + g * 16 + lo) * LD + hi * 8;
        bh[g][0] = *(const short8*)(zh + zo);
        bh[g][1] = *(const short8*)(zh + zo + 32);
        bl[g][0] = *(const short8*)(zl + zo);
        bl[g][1] = *(const short8*)(zl + zo + 32);
    }

    float bb[4], b2v[4];
    f32x4 qv[4];
    int   tt[4];
#pragma unroll
    for (int g = 0; g < 4; ++g) {
        bb[g] = -3.0e38f; b2v[g] = -3.0e38f; tt[g] = 0;
        qv[g][0] = qv[g][1] = qv[g][2] = qv[g][3] = -3.0e38f;
    }

    const int cbase = w * (NEMB / 4);
    const unsigned short* ehp = eh + (size_t)(cbase + lo) * LD + hi * 8;
    const unsigned short* elp = el + (size_t)(cbase + lo) * LD + hi * 8;

    short8 Aa0, Aa1, Aa2, Aa3; f32x4 Ae2;
    short8 Ba0, Ba1, Ba2, Ba3; f32x4 Be2;
    short8 Ca0, Ca1, Ca2, Ca3; f32x4 Ce2;

    K2_LOAD(A, 0);
    K2_LOAD(B, 1);
    K2_LOAD(C, 2);

    for (int tb = 0; tb < 27; tb += 3) {
        K2_COMP(A, tb);     K2_LOAD(A, tb + 3);
        K2_COMP(B, tb + 1); K2_LOAD(B, tb + 4);
        K2_COMP(C, tb + 2); K2_LOAD(C, tb + 5);
    }
    K2_COMP(A, 27); K2_LOAD(A, 30);
    K2_COMP(B, 28); K2_LOAD(B, 31);
    K2_COMP(C, 29);
    K2_COMP(A, 30);
    K2_COMP(B, 31);

    float ss[4];
    int   ii[4];
#pragma unroll
    for (int g = 0; g < 4; ++g) {
        float s0 = qv[g][0], s1 = qv[g][1], s2 = qv[g][2], s3 = qv[g][3];
        float M01 = fmaxf(s0, s1), L01 = fminf(s0, s1);
        float M23 = fmaxf(s2, s3), L23 = fminf(s2, s3);
        int   d01 = (s1 > s0) ? 1 : 0;
        int   d23 = (s3 > s2) ? 3 : 2;
        bool  cp  = (M23 > M01);
        float within2 = fmaxf(fminf(M01, M23), cp ? L23 : L01);
        int   dd  = cp ? d23 : d01;
        ii[g] = cbase + tt[g] * 16 + hi * 4 + dd;
        ss[g] = fmaxf(b2v[g], within2);
    }

#pragma unroll
    for (int off = 16; off <= 32; off <<= 1) {
#pragma unroll
        for (int g = 0; g < 4; ++g) {
            float ob = __shfl_xor(bb[g], off);
            float os = __shfl_xor(ss[g], off);
            int   oi = __shfl_xor(ii[g], off);
            ss[g] = fmaxf(fmaxf(fminf(bb[g], ob), os), ss[g]);
            ii[g] = (ob > bb[g]) ? oi : ii[g];
            bb[g] = fmaxf(bb[g], ob);
        }
    }

    __shared__ float Lb[4][64];
    __shared__ float Ls[4][64];
    __shared__ int   Li[4][64];
    if (lane < 16) {
#pragma unroll
        for (int g = 0; g < 4; ++g) {
            Lb[w][g * 16 + lane] = bb[g];
            Ls[w][g * 16 + lane] = ss[g];
            Li[w][g * 16 + lane] = ii[g];
        }
    }
    __syncthreads();

    if (tid < 64) {
        float B = Lb[0][tid], S = Ls[0][tid];
        int   I = Li[0][tid];
#pragma unroll
        for (int w2 = 1; w2 < 4; ++w2) {
            float ob = Lb[w2][tid], os = Ls[w2][tid];
            int   oi = Li[w2][tid];
            S = fmaxf(fmaxf(fminf(B, ob), os), S);
            I = (ob > B) ? oi : I;
            B = fmaxf(B, ob);
        }
        idx[rb + tid] = I;
        if (B - S < REFINE_THR_Q) {
            int p = atomicAdd(count, 1);
            list[p] = rb + tid;
        }
    }
}

// ---------------------------------------------------------------------------
// K3: exact f64 rescan of flagged near-tie rows.
// ---------------------------------------------------------------------------
__global__ __launch_bounds__(256) void k3_refine(const float* __restrict__ z,
                                                 const float* __restrict__ emb,
                                                 const int* __restrict__ count,
                                                 const int* __restrict__ list,
                                                 int* __restrict__ idx) {
    __shared__ double sv[256];
    __shared__ int    sx[256];
    int tid = threadIdx.x;
    int n = *count;
    for (int g = blockIdx.x; g < n; g += gridDim.x) {
        int row = list[g];
        const float4* zr4 = (const float4*)(z + (size_t)row * LD);
        float4 zv[16];
#pragma unroll
        for (int q = 0; q < 16; ++q) zv[q] = zr4[q];

        double best = 1.0e300;
        int bi = NEMB;
#pragma unroll 2
        for (int c = 0; c < 8; ++c) {
            int k = tid * 8 + c;
            const float4* er = (const float4*)(emb + (size_t)k * LD);
            double d0 = 0.0, d1 = 0.0, d2 = 0.0, d3 = 0.0;
#pragma unroll
            for (int q = 0; q < 16; ++q) {
                float4 e4 = er[q];
                double tx = (double)zv[q].x - (double)e4.x;
                double ty = (double)zv[q].y - (double)e4.y;
                double tz = (double)zv[q].z - (double)e4.z;
                double tw = (double)zv[q].w - (double)e4.w;
                d0 += tx * tx; d1 += ty * ty; d2 += tz * tz; d3 += tw * tw;
            }
            double d = (d0 + d1) + (d2 + d3);
            if (d < best) { best = d; bi = k; }
        }
        sv[tid] = best; sx[tid] = bi;
        __syncthreads();
        for (int s = 128; s > 0; s >>= 1) {
            if (tid < s) {
                if (sv[tid + s] < sv[tid] ||
                    (sv[tid + s] == sv[tid] && sx[tid + s] < sx[tid])) {
                    sv[tid] = sv[tid + s]; sx[tid] = sx[tid + s];
                }
            }
            __syncthreads();
        }
        if (tid == 0) idx[row] = sx[0];
        __syncthreads();
    }
}

// ---------------------------------------------------------------------------
// DEC v3 (MFMA split-bf16, 3 terms) — round-11/13 proven.
// ---------------------------------------------------------------------------
__global__ __launch_bounds__(256, 2) void k_dec(const int* __restrict__ idx,
                                                const float* __restrict__ emb,
                                                const unsigned short* __restrict__ w1h,
                                                const unsigned short* __restrict__ w1l,
                                                const float* __restrict__ b1,
                                                const unsigned short* __restrict__ w2h,
                                                const unsigned short* __restrict__ w2l,
                                                const float* __restrict__ b2,
                                                float* __restrict__ xrec,
                                                float* __restrict__ zq) {
    __shared__ float hds[4][16 * 68];
    int tid  = threadIdx.x;
    int lane = tid & 63;
    int w    = tid >> 6;
    int lo   = lane & 15;
    int hi   = lane >> 4;
    int rb   = blockIdx.x * 64 + w * 16;
    int row  = rb + lo;
    int ix   = idx[row];

    short8 zah[2], zal[2];
    {
        const float* er  = emb + (size_t)ix * LD + hi * 8;
        float* zqr = zq + (size_t)row * LD + hi * 8;
#pragma unroll
        for (int kt = 0; kt < 2; ++kt) {
            float4 a = *(const float4*)(er + kt * 32);
            float4 b = *(const float4*)(er + kt * 32 + 4);
            *(float4*)(zqr + kt * 32) = a;
            *(float4*)(zqr + kt * 32 + 4) = b;
            float v[8] = {a.x, a.y, a.z, a.w, b.x, b.y, b.z, b.w};
            unsigned short hh[8], ll[8];
#pragma unroll
            for (int q = 0; q < 8; ++q) {
                unsigned short hb = f2bf(v[q]);
                hh[q] = hb;
                ll[q] = f2bf(v[q] - bf2f(hb));
            }
            zah[kt] = *(short8*)hh;
            zal[kt] = *(short8*)ll;
        }
    }

#pragma unroll
    for (int jt = 0; jt < 4; ++jt) {
        float bj = b1[jt * 16 + lo];
        f32x4 c = {bj, bj, bj, bj};
#pragma unroll
        for (int kt = 0; kt < 2; ++kt) {
            short8 bh8 = *(const short8*)(w1h + (jt * 16 + lo) * LD + kt * 32 + hi * 8);
            short8 bl8 = *(const short8*)(w1l + (jt * 16 + lo) * LD + kt * 32 + hi * 8);
            c = __builtin_amdgcn_mfma_f32_16x16x32_bf16(zah[kt], bh8, c, 0, 0, 0);
            c = __builtin_amdgcn_mfma_f32_16x16x32_bf16(zah[kt], bl8, c, 0, 0, 0);
            c = __builtin_amdgcn_mfma_f32_16x16x32_bf16(zal[kt], bh8, c, 0, 0, 0);
        }
#pragma unroll
        for (int r = 0; r < 4; ++r)
            hds[w][(hi * 4 + r) * 68 + jt * 16 + lo] = fmaxf(c[r], 0.f);
    }
    __syncthreads();

    short8 hah[2], hal[2];
#pragma unroll
    for (int kt = 0; kt < 2; ++kt) {
        float4 a = *(const float4*)&hds[w][lo * 68 + kt * 32 + hi * 8];
        float4 b = *(const float4*)&hds[w][lo * 68 + kt * 32 + hi * 8 + 4];
        float v[8] = {a.x, a.y, a.z, a.w, b.x, b.y, b.z, b.w};
        unsigned short hh[8], ll[8];
#pragma unroll
        for (int q = 0; q < 8; ++q) {
            unsigned short hb = f2bf(v[q]);
            hh[q] = hb;
            ll[q] = f2bf(v[q] - bf2f(hb));
        }
        hah[kt] = *(short8*)hh;
        hal[kt] = *(short8*)ll;
    }

    for (int jt = 0; jt < 16; ++jt) {
        float bj = b2[jt * 16 + lo];
        f32x4 c = {bj, bj, bj, bj};
#pragma unroll
        for (int kt = 0; kt < 2; ++kt) {
            short8 bh8 = *(const short8*)(w2h + (jt * 16 + lo) * LD + kt * 32 + hi * 8);
            short8 bl8 = *(const short8*)(w2l + (jt * 16 + lo) * LD + kt * 32 + hi * 8);
            c = __builtin_amdgcn_mfma_f32_16x16x32_bf16(hah[kt], bh8, c, 0, 0, 0);
            c = __builtin_amdgcn_mfma_f32_16x16x32_bf16(hah[kt], bl8, c, 0, 0, 0);
            c = __builtin_amdgcn_mfma_f32_16x16x32_bf16(hal[kt], bh8, c, 0, 0, 0);
        }
#pragma unroll
        for (int r = 0; r < 4; ++r)
            xrec[(size_t)(rb + hi * 4 + r) * SD + jt * 16 + lo] = c[r];
    }
}

// ---------------------------------------------------------------------------
extern "C" void kernel_launch(void* const* d_in, const int* in_sizes, int n_in,
                              void* d_out, int out_size, void* d_ws, size_t ws_size,
                              hipStream_t stream) {
    const float* x   = (const float*)d_in[0];
    const float* ew1 = (const float*)d_in[1];
    const float* eb1 = (const float*)d_in[2];
    const float* ew2 = (const float*)d_in[3];
    const float* eb2 = (const float*)d_in[4];
    const float* emb = (const float*)d_in[5];
    const float* dw1 = (const float*)d_in[6];
    const float* db1 = (const float*)d_in[7];
    const float* dw2 = (const float*)d_in[8];
    const float* db2 = (const float*)d_in[9];

    float* out  = (float*)d_out;
    float* xrec = out;                               // [B,256] (written LAST)
    float* zE   = out + (size_t)BATCH * SD;          // [B,64]
    float* zQ   = zE + (size_t)BATCH * LD;           // [B,64]

    // transient scratch inside the x_recon region (dead once k_dec writes):
    char* xb = (char*)xrec;
    unsigned short* zh  = (unsigned short*)xb;                        // 4 MB
    unsigned short* zl  = (unsigned short*)(xb + (4u << 20));         // 4 MB
    unsigned short* eh  = (unsigned short*)(xb + (8u << 20));         // 256 KB
    unsigned short* el  = (unsigned short*)(xb + (8u << 20) + (NEMB * LD * 2)); // 256 KB
    float*          e2q = (float*)(xb + (9u << 20));                  // 8 KB

    char* ws = (char*)d_ws;
    int*  count = (int*)ws;                                     // 4 B
    int*  idxA  = (int*)(ws + 16384);                           // 128 KB
    int*  list  = (int*)(ws + 147456);                          // 128 KB
    unsigned short* w1h = (unsigned short*)(ws + 278528);       // 8 KB
    unsigned short* w1l = (unsigned short*)(ws + 286720);       // 8 KB
    unsigned short* w2h = (unsigned short*)(ws + 294912);       // 32 KB
    unsigned short* w2l = (unsigned short*)(ws + 327680);       // 32 KB

    hipLaunchKernelGGL(k0_all,    dim3(88),         dim3(256), 0, stream,
                       emb, dw1, dw2, e2q, eh, el, w1h, w1l, w2h, w2l, count);
    hipLaunchKernelGGL(k_enc,     dim3(BATCH / 64), dim3(512), 0, stream, x, ew1, eb1, ew2, eb2, zE, zh, zl);
    hipLaunchKernelGGL(k2_mfma,   dim3(BATCH / 64), dim3(256), 0, stream, zh, zl, eh, el, e2q, idxA, list, count);
    hipLaunchKernelGGL(k3_refine, dim3(128),        dim3(256), 0, stream, zE, emb, count, list, idxA);
    hipLaunchKernelGGL(k_dec,     dim3(BATCH / 64), dim3(256), 0, stream, idxA, emb, w1h, w1l, db1, w2h, w2l, db2, xrec, zQ);
}